// Round 1
// baseline (1373.341 us; speedup 1.0000x reference)
//
#include <hip/hip_runtime.h>

// Problem constants (fixed by reference): B=64, S=2048, UNITS=1024
#define BB   64
#define SS   2048
#define UU   1024
#define MM   (BB * SS)          // 131072 rows of the big GEMM

typedef unsigned short u16;
typedef unsigned int   u32;
typedef __attribute__((ext_vector_type(8))) short bf16x8;
typedef __attribute__((ext_vector_type(4))) float f32x4;

__device__ __forceinline__ u16 f2b(float f) {
    // round-to-nearest-even fp32 -> bf16
    u32 x = __float_as_uint(f);
    u32 r = (x + 0x7fffu + ((x >> 16) & 1u)) >> 16;
    return (u16)r;
}
__device__ __forceinline__ float b2f(u16 u) {
    return __uint_as_float(((u32)u) << 16);
}
__device__ __forceinline__ float fast_tanh(float x) {
    x = fminf(fmaxf(x, -15.f), 15.f);
    float e = __expf(2.f * x);
    return (e - 1.f) / (e + 1.f);
}

// ---------------- kernel 1: U_w [k][n] fp32 -> U_wT [n][k] bf16 ----------------
__global__ __launch_bounds__(256) void k_transpose_uw(const float* __restrict__ Uw,
                                                      u16* __restrict__ UwT) {
    __shared__ float tile[64][65];
    int n0 = blockIdx.x * 64, k0 = blockIdx.y * 64;
    int c = threadIdx.x & 63, r0 = threadIdx.x >> 6;   // r0 in 0..3
#pragma unroll
    for (int i = 0; i < 64; i += 4)
        tile[r0 + i][c] = Uw[(size_t)(k0 + r0 + i) * UU + n0 + c];
    __syncthreads();
#pragma unroll
    for (int i = 0; i < 64; i += 4)
        UwT[(size_t)(n0 + r0 + i) * UU + k0 + c] = f2b(tile[c][r0 + i]);
}

// ---------------- kernel 2: h fp32 -> bf16 ----------------
__global__ __launch_bounds__(256) void k_convert_h(const float* __restrict__ src,
                                                   u16* __restrict__ dst) {
    size_t i = ((size_t)blockIdx.x * 256 + threadIdx.x) * 8;
    float4 f0 = *(const float4*)(src + i);
    float4 f1 = *(const float4*)(src + i + 4);
    u16 t[8];
    t[0] = f2b(f0.x); t[1] = f2b(f0.y); t[2] = f2b(f0.z); t[3] = f2b(f0.w);
    t[4] = f2b(f1.x); t[5] = f2b(f1.y); t[6] = f2b(f1.z); t[7] = f2b(f1.w);
    *(uint4*)(dst + i) = *(uint4*)t;
}

// ---------------- kernel 3: Ws = s_prev @ W_w + W_b (fp32) ----------------
__global__ __launch_bounds__(256) void k_ws(const float* __restrict__ sp,
                                            const float* __restrict__ Ww,
                                            const float* __restrict__ Wb,
                                            float* __restrict__ Ws) {
    int u = blockIdx.x * 256 + threadIdx.x;   // 0..1023
    int b = blockIdx.y;
    const float* sprow = sp + (size_t)b * UU;
    float acc = 0.f;
#pragma unroll 4
    for (int k = 0; k < UU; ++k)
        acc = fmaf(sprow[k], Ww[(size_t)k * UU + u], acc);
    Ws[(size_t)b * UU + u] = acc + Wb[u];
}

// ---------------- kernel 4: fused GEMM + tanh·V_w row-reduce ----------------
// grid (8 n-tiles, 1024 m-tiles), 256 threads (4 waves, 2x2 of 64x64)
template <bool ABF16>
__global__ __launch_bounds__(256) void k_gemm(const void* __restrict__ Aptr,
                                              const u16* __restrict__ UwT,
                                              const float* __restrict__ Ws,
                                              const float* __restrict__ Ub,
                                              const float* __restrict__ Vw,
                                              float* __restrict__ scp) {
    __shared__ __align__(16) u16 As[128][72];   // [m][k], pad 8
    __shared__ __align__(16) u16 Bs[128][72];   // [n][k] (U_w^T), pad 8
    const int tid  = threadIdx.x;
    const int lane = tid & 63;
    const int wave = tid >> 6;
    const int wm = wave >> 1, wn = wave & 1;
    const int quad = lane >> 4, l15 = lane & 15;
    const int nt = blockIdx.x;                   // 0..7
    const int n0 = nt * 128;
    const size_t m0 = (size_t)blockIdx.y * 128;

    f32x4 acc[4][4];
#pragma unroll
    for (int i = 0; i < 4; ++i)
#pragma unroll
        for (int j = 0; j < 4; ++j) acc[i][j] = (f32x4){0.f, 0.f, 0.f, 0.f};

    const int sr = tid >> 3;         // 0..31 (staging row)
    const int sc = (tid & 7) * 8;    // 0..56 (staging col, 8 bf16)

    for (int kk = 0; kk < UU; kk += 64) {
        // ---- stage A tile [128 x 64] ----
        if (ABF16) {
            const u16* A = (const u16*)Aptr;
#pragma unroll
            for (int i = 0; i < 4; ++i) {
                int r = sr + i * 32;
                uint4 v = *(const uint4*)(A + (m0 + r) * UU + kk + sc);
                *(uint4*)(&As[r][sc]) = v;
            }
        } else {
            const float* A = (const float*)Aptr;
#pragma unroll
            for (int i = 0; i < 4; ++i) {
                int r = sr + i * 32;
                const float4* p = (const float4*)(A + (m0 + r) * UU + kk + sc);
                float4 f0 = p[0], f1 = p[1];
                u16 t[8];
                t[0] = f2b(f0.x); t[1] = f2b(f0.y); t[2] = f2b(f0.z); t[3] = f2b(f0.w);
                t[4] = f2b(f1.x); t[5] = f2b(f1.y); t[6] = f2b(f1.z); t[7] = f2b(f1.w);
                *(uint4*)(&As[r][sc]) = *(uint4*)t;
            }
        }
        // ---- stage B tile [128 x 64] from U_wT ----
#pragma unroll
        for (int i = 0; i < 4; ++i) {
            int r = sr + i * 32;
            uint4 v = *(const uint4*)(UwT + (size_t)(n0 + r) * UU + kk + sc);
            *(uint4*)(&Bs[r][sc]) = v;
        }
        __syncthreads();
#pragma unroll
        for (int k2 = 0; k2 < 64; k2 += 32) {
            bf16x8 a[4], b[4];
#pragma unroll
            for (int mi = 0; mi < 4; ++mi)
                a[mi] = *(const bf16x8*)(&As[wm * 64 + mi * 16 + l15][k2 + quad * 8]);
#pragma unroll
            for (int ni = 0; ni < 4; ++ni)
                b[ni] = *(const bf16x8*)(&Bs[wn * 64 + ni * 16 + l15][k2 + quad * 8]);
#pragma unroll
            for (int mi = 0; mi < 4; ++mi)
#pragma unroll
                for (int ni = 0; ni < 4; ++ni)
                    acc[mi][ni] = __builtin_amdgcn_mfma_f32_16x16x32_bf16(
                        a[mi], b[ni], acc[mi][ni], 0, 0, 0);
        }
        __syncthreads();
    }

    // ---- epilogue: score partial = sum_n tanh(acc + Ws[b][n] + Ub[n]) * Vw[n] ----
    const int bidx = (int)(m0 >> 11);            // m-tile lies in one batch row
    const float* wsrow = Ws + (size_t)bidx * UU;
    float wsv[4], ubv[4], vwv[4];
#pragma unroll
    for (int ni = 0; ni < 4; ++ni) {
        int ng = n0 + wn * 64 + ni * 16 + l15;
        wsv[ni] = wsrow[ng];
        ubv[ni] = Ub[ng];
        vwv[ni] = Vw[ng];
    }
#pragma unroll
    for (int mi = 0; mi < 4; ++mi) {
#pragma unroll
        for (int r = 0; r < 4; ++r) {
            float v = 0.f;
#pragma unroll
            for (int ni = 0; ni < 4; ++ni) {
                float x = acc[mi][ni][r] + wsv[ni] + ubv[ni];
                v = fmaf(fast_tanh(x), vwv[ni], v);
            }
            // reduce across the 16 lanes sharing this output row
#pragma unroll
            for (int off = 1; off < 16; off <<= 1)
                v += __shfl_xor(v, off, 64);
            if (l15 == 0) {
                size_t mg = m0 + wm * 64 + mi * 16 + quad * 4 + r;
                scp[mg * 16 + nt * 2 + wn] = v;
            }
        }
    }
}

// ---------------- kernel 5: softmax over S per batch ----------------
__global__ __launch_bounds__(256) void k_softmax(const float* __restrict__ scp,
                                                 float* __restrict__ wout) {
    int b = blockIdx.x, t = threadIdx.x;
    __shared__ float red[256];
    float sc[8];
    float lmax = -1e30f;
#pragma unroll
    for (int i = 0; i < 8; ++i) {
        int s = t + i * 256;
        const float4* p = (const float4*)(scp + ((size_t)b * SS + s) * 16);
        float4 a = p[0], c = p[1], d = p[2], e = p[3];
        float v = (a.x + a.y + a.z + a.w) + (c.x + c.y + c.z + c.w) +
                  (d.x + d.y + d.z + d.w) + (e.x + e.y + e.z + e.w);
        sc[i] = v;
        lmax = fmaxf(lmax, v);
    }
    red[t] = lmax;
    __syncthreads();
    for (int o = 128; o > 0; o >>= 1) {
        if (t < o) red[t] = fmaxf(red[t], red[t + o]);
        __syncthreads();
    }
    float mx = red[0];
    __syncthreads();
    float lsum = 0.f;
#pragma unroll
    for (int i = 0; i < 8; ++i) {
        sc[i] = __expf(sc[i] - mx);
        lsum += sc[i];
    }
    red[t] = lsum;
    __syncthreads();
    for (int o = 128; o > 0; o >>= 1) {
        if (t < o) red[t] += red[t + o];
        __syncthreads();
    }
    float inv = 1.f / red[0];
#pragma unroll
    for (int i = 0; i < 8; ++i)
        wout[(size_t)b * SS + t + i * 256] = sc[i] * inv;
}

// ---------------- kernel 6: context = sum_s w[b][s] * h[b][s][:] ----------------
// grid (8 s-chunks, 64 b); thread handles 4 consecutive u
template <bool HBF16>
__global__ __launch_bounds__(256) void k_context(const void* __restrict__ hptr,
                                                 const float* __restrict__ w,
                                                 float* __restrict__ ctx) {
    int b = blockIdx.y;
    int s0 = blockIdx.x * 256;
    int u = threadIdx.x * 4;
    const float* wrow = w + (size_t)b * SS + s0;
    float a0 = 0.f, a1 = 0.f, a2 = 0.f, a3 = 0.f;
    for (int i = 0; i < 256; ++i) {
        float wv = wrow[i];
        size_t base = ((size_t)b * SS + s0 + i) * UU + u;
        if (HBF16) {
            ushort4 hv = *(const ushort4*)((const u16*)hptr + base);
            a0 = fmaf(wv, b2f(hv.x), a0);
            a1 = fmaf(wv, b2f(hv.y), a1);
            a2 = fmaf(wv, b2f(hv.z), a2);
            a3 = fmaf(wv, b2f(hv.w), a3);
        } else {
            float4 hv = *(const float4*)((const float*)hptr + base);
            a0 = fmaf(wv, hv.x, a0);
            a1 = fmaf(wv, hv.y, a1);
            a2 = fmaf(wv, hv.z, a2);
            a3 = fmaf(wv, hv.w, a3);
        }
    }
    atomicAdd(&ctx[(size_t)b * UU + u + 0], a0);
    atomicAdd(&ctx[(size_t)b * UU + u + 1], a1);
    atomicAdd(&ctx[(size_t)b * UU + u + 2], a2);
    atomicAdd(&ctx[(size_t)b * UU + u + 3], a3);
}

extern "C" void kernel_launch(void* const* d_in, const int* in_sizes, int n_in,
                              void* d_out, int out_size, void* d_ws, size_t ws_size,
                              hipStream_t stream) {
    const float* s_prev = (const float*)d_in[0];
    const float* h      = (const float*)d_in[1];
    const float* Ww     = (const float*)d_in[2];
    const float* Wb     = (const float*)d_in[3];
    const float* Uw     = (const float*)d_in[4];
    const float* Ub     = (const float*)d_in[5];
    const float* Vw     = (const float*)d_in[6];
    // d_in[7] = V_b: softmax(x + c) == softmax(x) -> V_b cancels in both outputs.

    float* out = (float*)d_out;                 // [0,65536): context  [65536,196608): weights
    char* ws = (char*)d_ws;

    // workspace layout
    u16*   UwT = (u16*)ws;                                        // 2 MB
    float* Ws  = (float*)(ws + (size_t)(2 << 20));                // 256 KB
    float* scp = (float*)(ws + (size_t)(2 << 20) + (256 << 10));  // 131072*16*4 = 8 MB
    size_t offH = (size_t)(2 << 20) + (256 << 10) + ((size_t)8 << 20);
    u16*   hbf = (u16*)(ws + offH);
    const size_t hBytes = (size_t)MM * UU * 2;  // 256 MB
    const bool useBf16 = (ws_size >= offH + hBytes);

    // zero the context region (accumulated via atomics)
    hipMemsetAsync(out, 0, (size_t)BB * UU * sizeof(float), stream);

    k_transpose_uw<<<dim3(16, 16), 256, 0, stream>>>(Uw, UwT);
    k_ws<<<dim3(4, BB), 256, 0, stream>>>(s_prev, Ww, Wb, Ws);

    if (useBf16) {
        k_convert_h<<<(MM * (UU / 8)) / 256, 256, 0, stream>>>(h, hbf);
        k_gemm<true><<<dim3(8, MM / 128), 256, 0, stream>>>(hbf, UwT, Ws, Ub, Vw, scp);
    } else {
        k_gemm<false><<<dim3(8, MM / 128), 256, 0, stream>>>(h, UwT, Ws, Ub, Vw, scp);
    }

    k_softmax<<<BB, 256, 0, stream>>>(scp, out + (size_t)BB * UU);

    if (useBf16)
        k_context<true><<<dim3(8, BB), 256, 0, stream>>>(hbf, out + (size_t)BB * UU, out);
    else
        k_context<false><<<dim3(8, BB), 256, 0, stream>>>(h, out + (size_t)BB * UU, out);
}

// Round 2
// 1262.076 us; speedup vs baseline: 1.0882x; 1.0882x over previous
//
#include <hip/hip_runtime.h>

// Problem constants (fixed by reference): B=64, S=2048, UNITS=1024
#define BB   64
#define SS   2048
#define UU   1024
#define MM   (BB * SS)          // 131072 rows of the big GEMM

typedef unsigned short u16;
typedef unsigned int   u32;
typedef __attribute__((ext_vector_type(8))) short bf16x8;
typedef __attribute__((ext_vector_type(4))) float f32x4;

__device__ __forceinline__ u16 f2b(float f) {
    // round-to-nearest-even fp32 -> bf16
    u32 x = __float_as_uint(f);
    u32 r = (x + 0x7fffu + ((x >> 16) & 1u)) >> 16;
    return (u16)r;
}
__device__ __forceinline__ float b2f(u16 u) {
    return __uint_as_float(((u32)u) << 16);
}
__device__ __forceinline__ float fast_tanh(float x) {
    x = fminf(fmaxf(x, -15.f), 15.f);
    float e = __expf(2.f * x);
    return (e - 1.f) / (e + 1.f);
}
// async global->LDS 16B per lane; LDS dest = wave-uniform base + lane*16
__device__ __forceinline__ void async_copy16(const u16* gp, u16* lp) {
    __builtin_amdgcn_global_load_lds(
        (const __attribute__((address_space(1))) unsigned int*)gp,
        (__attribute__((address_space(3))) unsigned int*)lp, 16, 0, 0);
}

// ---------------- kernel 1: U_w [k][n] fp32 -> U_wT [n][k] bf16 ----------------
__global__ __launch_bounds__(256) void k_transpose_uw(const float* __restrict__ Uw,
                                                      u16* __restrict__ UwT) {
    __shared__ float tile[64][65];
    int n0 = blockIdx.x * 64, k0 = blockIdx.y * 64;
    int c = threadIdx.x & 63, r0 = threadIdx.x >> 6;   // r0 in 0..3
#pragma unroll
    for (int i = 0; i < 64; i += 4)
        tile[r0 + i][c] = Uw[(size_t)(k0 + r0 + i) * UU + n0 + c];
    __syncthreads();
#pragma unroll
    for (int i = 0; i < 64; i += 4)
        UwT[(size_t)(n0 + r0 + i) * UU + k0 + c] = f2b(tile[c][r0 + i]);
}

// ---------------- kernel 2: h fp32 -> bf16 ----------------
__global__ __launch_bounds__(256) void k_convert_h(const float* __restrict__ src,
                                                   u16* __restrict__ dst) {
    size_t i = ((size_t)blockIdx.x * 256 + threadIdx.x) * 8;
    float4 f0 = *(const float4*)(src + i);
    float4 f1 = *(const float4*)(src + i + 4);
    u16 t[8];
    t[0] = f2b(f0.x); t[1] = f2b(f0.y); t[2] = f2b(f0.z); t[3] = f2b(f0.w);
    t[4] = f2b(f1.x); t[5] = f2b(f1.y); t[6] = f2b(f1.z); t[7] = f2b(f1.w);
    *(uint4*)(dst + i) = *(uint4*)t;
}

// ---------------- kernel 3: Ws = s_prev @ W_w + W_b (fp32), split-K atomic ----
// grid (4 u-blocks, 64 b, 4 k-slices); Ws must be zeroed first, Wb added by slice 0
__global__ __launch_bounds__(256) void k_ws(const float* __restrict__ sp,
                                            const float* __restrict__ Ww,
                                            const float* __restrict__ Wb,
                                            float* __restrict__ Ws) {
    int u = blockIdx.x * 256 + threadIdx.x;   // 0..1023
    int b = blockIdx.y;
    int k0 = blockIdx.z * 256;
    const float* sprow = sp + (size_t)b * UU + k0;
    float acc = (blockIdx.z == 0) ? Wb[u] : 0.f;
#pragma unroll 4
    for (int k = 0; k < 256; ++k)
        acc = fmaf(sprow[k], Ww[(size_t)(k0 + k) * UU + u], acc);
    atomicAdd(&Ws[(size_t)b * UU + u], acc);
}

// ---------------- kernel 4: fused GEMM + tanh·V_w row-reduce (bf16 fast path) --
// 1-D grid of 8192 blocks; XCD-aware swizzle: mt = g*8+(bid&7), nt = (bid>>3)&7
// so the 8 n-tiles of one A m-tile all land on one XCD (bid%8) for L2 reuse.
__global__ __launch_bounds__(256) void k_gemm_lds(const u16* __restrict__ A,
                                                  const u16* __restrict__ UwT,
                                                  const float* __restrict__ Ws,
                                                  const float* __restrict__ Ub,
                                                  const float* __restrict__ Vw,
                                                  float* __restrict__ scp) {
    __shared__ __align__(16) u16 As[128 * 64];   // [m][k] rows of 64 bf16, XOR-swizzled
    __shared__ __align__(16) u16 Bs[128 * 64];   // [n][k]
    const int tid  = threadIdx.x;
    const int lane = tid & 63;
    const int wave = tid >> 6;
    const int wm = wave >> 1, wn = wave & 1;
    const int quad = lane >> 4, l15 = lane & 15;

    const int bid = blockIdx.x;
    const int g   = bid >> 6;
    const int mt  = g * 8 + (bid & 7);
    const int nt  = (bid >> 3) & 7;
    const int n0  = nt * 128;
    const size_t m0 = (size_t)mt * 128;

    // staging lane geometry: lane L covers row srow of its 8-row group,
    // fetches global chunk (L&7)^srow so that LDS pos p holds chunk p^row.
    const int srow   = lane >> 3;             // 0..7
    const int schunk = (lane & 7) ^ srow;     // chunk to FETCH (8 bf16 = 16B)
    const size_t lane_off = (size_t)srow * UU + (size_t)schunk * 8;

    f32x4 acc[4][4];
#pragma unroll
    for (int i = 0; i < 4; ++i)
#pragma unroll
        for (int j = 0; j < 4; ++j) acc[i][j] = (f32x4){0.f, 0.f, 0.f, 0.f};

    for (int kk = 0; kk < UU; kk += 64) {
        // ---- stage A tile [128 x 64] : 4 waves x 4 instr x 1KB ----
#pragma unroll
        for (int i = 0; i < 4; ++i) {
            const int gi = wave * 4 + i;                      // 8-row group 0..15
            async_copy16(A + (m0 + gi * 8) * UU + kk + lane_off, As + gi * 512);
        }
#pragma unroll
        for (int i = 0; i < 4; ++i) {
            const int gi = wave * 4 + i;
            async_copy16(UwT + (size_t)(n0 + gi * 8) * UU + kk + lane_off, Bs + gi * 512);
        }
        __syncthreads();
#pragma unroll
        for (int k2 = 0; k2 < 2; ++k2) {
            const int chunk = quad + k2 * 4;                  // k-chunk 0..7
            const int pos = chunk ^ (l15 & 7);                // XOR de-swizzle
            bf16x8 a[4], b[4];
#pragma unroll
            for (int mi = 0; mi < 4; ++mi) {
                int r = wm * 64 + mi * 16 + l15;
                a[mi] = *(const bf16x8*)(As + r * 64 + pos * 8);
            }
#pragma unroll
            for (int ni = 0; ni < 4; ++ni) {
                int r = wn * 64 + ni * 16 + l15;
                b[ni] = *(const bf16x8*)(Bs + r * 64 + pos * 8);
            }
#pragma unroll
            for (int mi = 0; mi < 4; ++mi)
#pragma unroll
                for (int ni = 0; ni < 4; ++ni)
                    acc[mi][ni] = __builtin_amdgcn_mfma_f32_16x16x32_bf16(
                        a[mi], b[ni], acc[mi][ni], 0, 0, 0);
        }
        __syncthreads();
    }

    // ---- epilogue: score partial = sum_n tanh(acc + Ws[b][n] + Ub[n]) * Vw[n] ----
    const int bidx = (int)(m0 >> 11);            // m-tile lies in one batch row
    const float* wsrow = Ws + (size_t)bidx * UU;
    float wsv[4], ubv[4], vwv[4];
#pragma unroll
    for (int ni = 0; ni < 4; ++ni) {
        int ng = n0 + wn * 64 + ni * 16 + l15;
        wsv[ni] = wsrow[ng];
        ubv[ni] = Ub[ng];
        vwv[ni] = Vw[ng];
    }
#pragma unroll
    for (int mi = 0; mi < 4; ++mi) {
#pragma unroll
        for (int r = 0; r < 4; ++r) {
            float v = 0.f;
#pragma unroll
            for (int ni = 0; ni < 4; ++ni) {
                float x = acc[mi][ni][r] + wsv[ni] + ubv[ni];
                v = fmaf(fast_tanh(x), vwv[ni], v);
            }
#pragma unroll
            for (int off = 1; off < 16; off <<= 1)
                v += __shfl_xor(v, off, 64);
            if (l15 == 0) {
                size_t mg = m0 + wm * 64 + mi * 16 + quad * 4 + r;
                scp[mg * 16 + nt * 2 + wn] = v;
            }
        }
    }
}

// ---------------- kernel 4b: fp32-input fallback (ws too small for hbf) -------
__global__ __launch_bounds__(256) void k_gemm_f32(const float* __restrict__ Aptr,
                                                  const u16* __restrict__ UwT,
                                                  const float* __restrict__ Ws,
                                                  const float* __restrict__ Ub,
                                                  const float* __restrict__ Vw,
                                                  float* __restrict__ scp) {
    __shared__ __align__(16) u16 As[128][72];
    __shared__ __align__(16) u16 Bs[128][72];
    const int tid  = threadIdx.x;
    const int lane = tid & 63;
    const int wave = tid >> 6;
    const int wm = wave >> 1, wn = wave & 1;
    const int quad = lane >> 4, l15 = lane & 15;
    const int nt = blockIdx.x;
    const int n0 = nt * 128;
    const size_t m0 = (size_t)blockIdx.y * 128;

    f32x4 acc[4][4];
#pragma unroll
    for (int i = 0; i < 4; ++i)
#pragma unroll
        for (int j = 0; j < 4; ++j) acc[i][j] = (f32x4){0.f, 0.f, 0.f, 0.f};

    const int sr = tid >> 3;
    const int sc = (tid & 7) * 8;

    for (int kk = 0; kk < UU; kk += 64) {
#pragma unroll
        for (int i = 0; i < 4; ++i) {
            int r = sr + i * 32;
            const float4* p = (const float4*)(Aptr + (m0 + r) * UU + kk + sc);
            float4 f0 = p[0], f1 = p[1];
            u16 t[8];
            t[0] = f2b(f0.x); t[1] = f2b(f0.y); t[2] = f2b(f0.z); t[3] = f2b(f0.w);
            t[4] = f2b(f1.x); t[5] = f2b(f1.y); t[6] = f2b(f1.z); t[7] = f2b(f1.w);
            *(uint4*)(&As[r][sc]) = *(uint4*)t;
        }
#pragma unroll
        for (int i = 0; i < 4; ++i) {
            int r = sr + i * 32;
            uint4 v = *(const uint4*)(UwT + (size_t)(n0 + r) * UU + kk + sc);
            *(uint4*)(&Bs[r][sc]) = v;
        }
        __syncthreads();
#pragma unroll
        for (int k2 = 0; k2 < 64; k2 += 32) {
            bf16x8 a[4], b[4];
#pragma unroll
            for (int mi = 0; mi < 4; ++mi)
                a[mi] = *(const bf16x8*)(&As[wm * 64 + mi * 16 + l15][k2 + quad * 8]);
#pragma unroll
            for (int ni = 0; ni < 4; ++ni)
                b[ni] = *(const bf16x8*)(&Bs[wn * 64 + ni * 16 + l15][k2 + quad * 8]);
#pragma unroll
            for (int mi = 0; mi < 4; ++mi)
#pragma unroll
                for (int ni = 0; ni < 4; ++ni)
                    acc[mi][ni] = __builtin_amdgcn_mfma_f32_16x16x32_bf16(
                        a[mi], b[ni], acc[mi][ni], 0, 0, 0);
        }
        __syncthreads();
    }

    const int bidx = (int)(m0 >> 11);
    const float* wsrow = Ws + (size_t)bidx * UU;
    float wsv[4], ubv[4], vwv[4];
#pragma unroll
    for (int ni = 0; ni < 4; ++ni) {
        int ng = n0 + wn * 64 + ni * 16 + l15;
        wsv[ni] = wsrow[ng];
        ubv[ni] = Ub[ng];
        vwv[ni] = Vw[ng];
    }
#pragma unroll
    for (int mi = 0; mi < 4; ++mi) {
#pragma unroll
        for (int r = 0; r < 4; ++r) {
            float v = 0.f;
#pragma unroll
            for (int ni = 0; ni < 4; ++ni) {
                float x = acc[mi][ni][r] + wsv[ni] + ubv[ni];
                v = fmaf(fast_tanh(x), vwv[ni], v);
            }
#pragma unroll
            for (int off = 1; off < 16; off <<= 1)
                v += __shfl_xor(v, off, 64);
            if (l15 == 0) {
                size_t mg = m0 + wm * 64 + mi * 16 + quad * 4 + r;
                scp[mg * 16 + nt * 2 + wn] = v;
            }
        }
    }
}

// ---------------- kernel 5: softmax over S per batch ----------------
__global__ __launch_bounds__(256) void k_softmax(const float* __restrict__ scp,
                                                 float* __restrict__ wout) {
    int b = blockIdx.x, t = threadIdx.x;
    __shared__ float red[256];
    float sc[8];
    float lmax = -1e30f;
#pragma unroll
    for (int i = 0; i < 8; ++i) {
        int s = t + i * 256;
        const float4* p = (const float4*)(scp + ((size_t)b * SS + s) * 16);
        float4 a = p[0], c = p[1], d = p[2], e = p[3];
        float v = (a.x + a.y + a.z + a.w) + (c.x + c.y + c.z + c.w) +
                  (d.x + d.y + d.z + d.w) + (e.x + e.y + e.z + e.w);
        sc[i] = v;
        lmax = fmaxf(lmax, v);
    }
    red[t] = lmax;
    __syncthreads();
    for (int o = 128; o > 0; o >>= 1) {
        if (t < o) red[t] = fmaxf(red[t], red[t + o]);
        __syncthreads();
    }
    float mx = red[0];
    __syncthreads();
    float lsum = 0.f;
#pragma unroll
    for (int i = 0; i < 8; ++i) {
        sc[i] = __expf(sc[i] - mx);
        lsum += sc[i];
    }
    red[t] = lsum;
    __syncthreads();
    for (int o = 128; o > 0; o >>= 1) {
        if (t < o) red[t] += red[t + o];
        __syncthreads();
    }
    float inv = 1.f / red[0];
#pragma unroll
    for (int i = 0; i < 8; ++i)
        wout[(size_t)b * SS + t + i * 256] = sc[i] * inv;
}

// ---------------- kernel 6: context = sum_s w[b][s] * h[b][s][:] ----------------
// grid (16 s-chunks, 64 b); thread handles 4 consecutive u
template <bool HBF16>
__global__ __launch_bounds__(256) void k_context(const void* __restrict__ hptr,
                                                 const float* __restrict__ w,
                                                 float* __restrict__ ctx) {
    int b = blockIdx.y;
    int s0 = blockIdx.x * 128;
    int u = threadIdx.x * 4;
    const float* wrow = w + (size_t)b * SS + s0;
    float a0 = 0.f, a1 = 0.f, a2 = 0.f, a3 = 0.f;
    for (int i = 0; i < 128; ++i) {
        float wv = wrow[i];
        size_t base = ((size_t)b * SS + s0 + i) * UU + u;
        if (HBF16) {
            ushort4 hv = *(const ushort4*)((const u16*)hptr + base);
            a0 = fmaf(wv, b2f(hv.x), a0);
            a1 = fmaf(wv, b2f(hv.y), a1);
            a2 = fmaf(wv, b2f(hv.z), a2);
            a3 = fmaf(wv, b2f(hv.w), a3);
        } else {
            float4 hv = *(const float4*)((const float*)hptr + base);
            a0 = fmaf(wv, hv.x, a0);
            a1 = fmaf(wv, hv.y, a1);
            a2 = fmaf(wv, hv.z, a2);
            a3 = fmaf(wv, hv.w, a3);
        }
    }
    atomicAdd(&ctx[(size_t)b * UU + u + 0], a0);
    atomicAdd(&ctx[(size_t)b * UU + u + 1], a1);
    atomicAdd(&ctx[(size_t)b * UU + u + 2], a2);
    atomicAdd(&ctx[(size_t)b * UU + u + 3], a3);
}

extern "C" void kernel_launch(void* const* d_in, const int* in_sizes, int n_in,
                              void* d_out, int out_size, void* d_ws, size_t ws_size,
                              hipStream_t stream) {
    const float* s_prev = (const float*)d_in[0];
    const float* h      = (const float*)d_in[1];
    const float* Ww     = (const float*)d_in[2];
    const float* Wb     = (const float*)d_in[3];
    const float* Uw     = (const float*)d_in[4];
    const float* Ub     = (const float*)d_in[5];
    const float* Vw     = (const float*)d_in[6];
    // d_in[7] = V_b: softmax(x + c) == softmax(x) -> V_b cancels in both outputs.

    float* out = (float*)d_out;                 // [0,65536): context  [65536,196608): weights
    char* ws = (char*)d_ws;

    // workspace layout
    u16*   UwT = (u16*)ws;                                        // 2 MB
    float* Ws  = (float*)(ws + (size_t)(2 << 20));                // 256 KB
    float* scp = (float*)(ws + (size_t)(2 << 20) + (256 << 10));  // 131072*16*4 = 8 MB
    size_t offH = (size_t)(2 << 20) + (256 << 10) + ((size_t)8 << 20);
    u16*   hbf = (u16*)(ws + offH);
    const size_t hBytes = (size_t)MM * UU * 2;  // 256 MB
    const bool useBf16 = (ws_size >= offH + hBytes);

    // zero atomically-accumulated buffers
    hipMemsetAsync(out, 0, (size_t)BB * UU * sizeof(float), stream);
    hipMemsetAsync(Ws, 0, (size_t)BB * UU * sizeof(float), stream);

    k_transpose_uw<<<dim3(16, 16), 256, 0, stream>>>(Uw, UwT);
    k_ws<<<dim3(4, BB, 4), 256, 0, stream>>>(s_prev, Ww, Wb, Ws);

    if (useBf16) {
        k_convert_h<<<(MM * (UU / 8)) / 256, 256, 0, stream>>>(h, hbf);
        k_gemm_lds<<<8192, 256, 0, stream>>>(hbf, UwT, Ws, Ub, Vw, scp);
    } else {
        k_gemm_f32<<<dim3(8, MM / 128), 256, 0, stream>>>(h, UwT, Ws, Ub, Vw, scp);
    }

    k_softmax<<<BB, 256, 0, stream>>>(scp, out + (size_t)BB * UU);

    if (useBf16)
        k_context<true><<<dim3(16, BB), 256, 0, stream>>>(hbf, out + (size_t)BB * UU, out);
    else
        k_context<false><<<dim3(16, BB), 256, 0, stream>>>(h, out + (size_t)BB * UU, out);
}